// Round 4
// baseline (47.563 us; speedup 1.0000x reference)
//
#include <hip/hip_runtime.h>

#define NT 128          // threads per block
#define BJ 128          // j-tile width
#define NI 2            // i-rows per thread -> BI = 256

struct Row {
    float x, y, l, r, b, t, aie;   // box params; aie = area_i + EPS
    float iou, rep;                // accumulators (v_j-weighted)
};

__device__ __forceinline__ void proc(Row& R, const float4& bx, const float4& ax, float vj) {
    const float RM = 0.06f, EPSf = 1e-6f;
    float iw    = fmaxf(fminf(R.r, bx.y) - fmaxf(R.l, bx.x), 0.f);
    float ih    = fmaxf(fminf(R.t, bx.w) - fmaxf(R.b, bx.z), 0.f);
    float inter = iw * ih;
    float uni   = (R.aie + ax.z) - inter;          // >= EPS
    float iou   = inter * __builtin_amdgcn_rcpf(uni);
    float dx    = R.x - ax.x;
    float dy    = R.y - ax.y;
    float dist  = __builtin_amdgcn_sqrtf(fmaf(dx, dx, fmaf(dy, dy, EPSf)));
    float rp    = fmaxf(RM - dist, 0.f);
    R.iou = fmaf(iou, vj, R.iou);
    R.rep = fmaf(rp * rp, vj, R.rep);
}

// M = 0 full (j>i structurally), 1 diagonal (j>i <=> t>tid), 2 skip
template<int M0, int M1>
__device__ __forceinline__ void iloop(const float4* __restrict__ sh_box,
                                      const float4* __restrict__ sh_aux,
                                      int jcount, int tid, Row& R0, Row& R1)
{
    #pragma unroll 8
    for (int t = 0; t < jcount; ++t) {
        float4 bx = sh_box[t];   // broadcast LDS reads
        float4 ax = sh_aux[t];
        if (M0 != 2) {
            float vj = ax.w;
            if (M0 == 1) vj = (t > tid) ? vj : 0.f;
            proc(R0, bx, ax, vj);
        }
        if (M1 != 2) {
            float vj = ax.w;
            if (M1 == 1) vj = (t > tid) ? vj : 0.f;
            proc(R1, bx, ax, vj);
        }
    }
}

__device__ __forceinline__ void load_row(const float* __restrict__ pos,
                                         const float* __restrict__ size,
                                         const float* __restrict__ valid,
                                         int i, int n, Row& R, float& vi)
{
    const float EPSf = 1e-6f;
    R.x = 0.f; R.y = 0.f; R.l = 0.f; R.r = 0.f; R.b = 0.f; R.t = 0.f;
    R.aie = EPSf; R.iou = 0.f; R.rep = 0.f; vi = 0.f;
    if (i < n) {
        R.x = pos[2 * i];
        R.y = pos[2 * i + 1];
        float w = size[2 * i];
        float h = size[2 * i + 1];
        R.l = R.x - 0.5f * w;  R.r = R.x + 0.5f * w;
        R.b = R.y - 0.5f * h;  R.t = R.y + 0.5f * h;
        R.aie = w * h + EPSf;
        vi = valid[i];
    }
}

__global__ __launch_bounds__(NT) void ol_pair_kernel(
    const float* __restrict__ pos, const float* __restrict__ size,
    const float* __restrict__ valid, double* __restrict__ part,
    int n, int Tj, int P)
{
    __shared__ float4 sh_box[BJ];
    __shared__ float4 sh_aux[BJ];

    int tid = (int)threadIdx.x;
    int bid = (int)blockIdx.x;

    // Row it has (Tj - 2*it) j-tiles; cumulative C(it) = it*(Tj - it + 1).
    double Tp1 = (double)Tj + 1.0;
    int it = (int)((Tp1 - sqrt(Tp1 * Tp1 - 4.0 * (double)bid)) * 0.5);
    if (it < 0) it = 0;
    while ((it + 1) * (Tj - it) <= bid) ++it;          // C(it+1) <= bid -> row further down
    while (it > 0 && it * (Tj - it + 1) > bid) --it;   // C(it)   >  bid -> row further up
    int jt = 2 * it + (bid - it * (Tj - it + 1));

    int ibase = it * (NI * NT);
    int jbase = jt * BJ;

    Row R0, R1;
    float vi0, vi1;
    load_row(pos, size, valid, ibase + tid,      n, R0, vi0);
    load_row(pos, size, valid, ibase + NT + tid, n, R1, vi1);

    // Stage j-tile (l,r,b,t | x,y,area,valid); pad with valid=0.
    int j = jbase + tid;
    if (j < n) {
        float xj = pos[2 * j];
        float yj = pos[2 * j + 1];
        float wj = size[2 * j];
        float hj = size[2 * j + 1];
        sh_box[tid] = make_float4(xj - 0.5f * wj, xj + 0.5f * wj,
                                  yj - 0.5f * hj, yj + 0.5f * hj);
        sh_aux[tid] = make_float4(xj, yj, wj * hj, valid[j]);
    } else {
        sh_box[tid] = make_float4(0.f, 0.f, 0.f, 0.f);
        sh_aux[tid] = make_float4(0.f, 0.f, 0.f, 0.f);
    }
    __syncthreads();

    int jcount = min(BJ, n - jbase);
    if (jcount > 0) {
        if (jt == 2 * it)           iloop<1, 2>(sh_box, sh_aux, jcount, tid, R0, R1);
        else if (jt == 2 * it + 1)  iloop<0, 1>(sh_box, sh_aux, jcount, tid, R0, R1);
        else                        iloop<0, 0>(sh_box, sh_aux, jcount, tid, R0, R1);
    }

    // Fold v_i, then reduce the block's 2 waves.
    float s_iou = vi0 * R0.iou + vi1 * R1.iou;
    float s_rep = vi0 * R0.rep + vi1 * R1.rep;
    for (int off = 32; off > 0; off >>= 1) {
        s_iou += __shfl_down(s_iou, off);
        s_rep += __shfl_down(s_rep, off);
    }
    __shared__ float red[2][2];
    int lane = tid & 63;
    int wid  = tid >> 6;
    if (lane == 0) { red[0][wid] = s_iou; red[1][wid] = s_rep; }
    __syncthreads();
    if (tid == 0) {
        part[bid]     = (double)red[0][0] + (double)red[0][1];
        part[P + bid] = (double)red[1][0] + (double)red[1][1];
    }
}

__global__ __launch_bounds__(256) void ol_finalize(
    const double* __restrict__ part, int P,
    const float* __restrict__ valid, int n, float* __restrict__ out)
{
    double a = 0.0, b = 0.0, S = 0.0, Q = 0.0;
    for (int k = (int)threadIdx.x; k < P; k += 256) {
        a += part[k];
        b += part[P + k];
    }
    for (int k = (int)threadIdx.x; k < n; k += 256) {
        double v = (double)valid[k];
        S += v;
        Q += v * v;
    }
    __shared__ double sa[256], sb[256], ss[256], sq[256];
    sa[threadIdx.x] = a; sb[threadIdx.x] = b; ss[threadIdx.x] = S; sq[threadIdx.x] = Q;
    __syncthreads();
    for (int s = 128; s > 0; s >>= 1) {
        if ((int)threadIdx.x < s) {
            sa[threadIdx.x] += sa[threadIdx.x + s];
            sb[threadIdx.x] += sb[threadIdx.x + s];
            ss[threadIdx.x] += ss[threadIdx.x + s];
            sq[threadIdx.x] += sq[threadIdx.x + s];
        }
        __syncthreads();
    }
    if (threadIdx.x == 0) {
        double denom = 0.5 * (ss[0] * ss[0] - sq[0]) + 1e-6;   // sum_{i<j} v_i v_j + EPS
        out[0] = (float)(0.5 * ((sa[0] + sb[0]) / denom));     // WEIGHT * RAMP = 0.5
    }
}

extern "C" void kernel_launch(void* const* d_in, const int* in_sizes, int n_in,
                              void* d_out, int out_size, void* d_ws, size_t ws_size,
                              hipStream_t stream) {
    const float* pos   = (const float*)d_in[0];
    const float* size  = (const float*)d_in[1];
    const float* valid = (const float*)d_in[2];
    float* out = (float*)d_out;
    double* ws = (double*)d_ws;
    int n  = in_sizes[2];                    // valid_mask length = N
    int Ti = (n + NI * NT - 1) / (NI * NT);  // 32 i-tiles (256 rows each)
    int Tj = (n + BJ - 1) / BJ;              // 64 j-tiles (128 cols each)
    int P  = Ti * (Tj - Ti + 1);             // 1056 blocks

    ol_pair_kernel<<<P, NT, 0, stream>>>(pos, size, valid, ws, n, Tj, P);
    ol_finalize<<<1, 256, 0, stream>>>(ws, P, valid, n, out);
}

// Round 5
// 45.004 us; speedup vs baseline: 1.0569x; 1.0569x over previous
//
#include <hip/hip_runtime.h>

#define TILE 64   // 64x64 tile per block, one wave

template<bool DIAG>
__device__ __forceinline__ void inner_loop(
    const float4* __restrict__ sh_box, const float4* __restrict__ sh_aux,
    int jcount, int tid,
    float li, float ri, float bi, float ti, float xi, float yi, float aie,
    float& s_iou, float& s_rep)
{
    const float RM = 0.06f, EPSf = 1e-6f;
    #pragma unroll 8
    for (int t = 0; t < jcount; ++t) {
        float4 bx = sh_box[t];   // l, r, b, t   (broadcast LDS read)
        float4 ax = sh_aux[t];   // x, y, area, valid_j

        float iw    = fmaxf(fminf(ri, bx.y) - fmaxf(li, bx.x), 0.f);
        float ih    = fmaxf(fminf(ti, bx.w) - fmaxf(bi, bx.z), 0.f);
        float inter = iw * ih;
        float uni   = (aie + ax.z) - inter;                  // >= EPS
        float rc    = __builtin_amdgcn_rcpf(uni);

        float vj = ax.w;
        if (DIAG) vj = (t > tid) ? vj : 0.f;                 // j > i on diagonal tile

        float dx   = xi - ax.x;
        float dy   = yi - ax.y;
        float dist = __builtin_amdgcn_sqrtf(fmaf(dx, dx, fmaf(dy, dy, EPSf)));
        float rp   = fmaxf(RM - dist, 0.f);

        s_iou = fmaf(inter * rc, vj, s_iou);
        s_rep = fmaf(rp * rp, vj, s_rep);
    }
}

__global__ __launch_bounds__(TILE) void ol_pair_kernel(
    const float* __restrict__ pos, const float* __restrict__ size,
    const float* __restrict__ valid, float* __restrict__ part,
    int n, int T, int P)
{
    __shared__ float4 sh_box[TILE];
    __shared__ float4 sh_aux[TILE];

    const float EPSf = 1e-6f;
    int tid = (int)threadIdx.x;
    int bid = (int)blockIdx.x;

    // Decode bid -> (it, jt), jt >= it. offset(r) = r*(2T - r + 1)/2.
    float Tf = (float)T;
    float disc = (2.f * Tf + 1.f) * (2.f * Tf + 1.f) - 8.f * (float)bid;
    int it = (int)(((2.f * Tf + 1.f) - sqrtf(fmaxf(disc, 0.f))) * 0.5f);
    it = max(0, min(it, T - 1));
    while ((it + 1) * (2 * T - it) / 2 <= bid) ++it;
    while (it > 0 && it * (2 * T - it + 1) / 2 > bid) --it;
    int jt = it + (bid - it * (2 * T - it + 1) / 2);

    int i     = it * TILE + tid;
    int jbase = jt * TILE;

    const float2* pos2  = (const float2*)pos;
    const float2* size2 = (const float2*)size;

    // This thread's i-box (v_i folded in at the end).
    float xi = 0.f, yi = 0.f, li = 0.f, ri = 0.f, bi = 0.f, ti = 0.f;
    float aie = EPSf, vi = 0.f;
    if (i < n) {
        float2 p = pos2[i];
        float2 s = size2[i];
        xi = p.x;  yi = p.y;
        li = p.x - 0.5f * s.x;  ri = p.x + 0.5f * s.x;
        bi = p.y - 0.5f * s.y;  ti = p.y + 0.5f * s.y;
        aie = s.x * s.y + EPSf;
        vi = valid[i];
    }

    // Stage j-tile; pad with valid=0.
    int j = jbase + tid;
    if (j < n) {
        float2 p = pos2[j];
        float2 s = size2[j];
        sh_box[tid] = make_float4(p.x - 0.5f * s.x, p.x + 0.5f * s.x,
                                  p.y - 0.5f * s.y, p.y + 0.5f * s.y);
        sh_aux[tid] = make_float4(p.x, p.y, s.x * s.y, valid[j]);
    } else {
        sh_box[tid] = make_float4(0.f, 0.f, 0.f, 0.f);
        sh_aux[tid] = make_float4(0.f, 0.f, 0.f, 0.f);
    }
    __syncthreads();

    float s_iou = 0.f, s_rep = 0.f;
    int jcount = min(TILE, n - jbase);
    if (jcount > 0) {
        if (it == jt)
            inner_loop<true >(sh_box, sh_aux, jcount, tid, li, ri, bi, ti, xi, yi, aie,
                              s_iou, s_rep);
        else
            inner_loop<false>(sh_box, sh_aux, jcount, tid, li, ri, bi, ti, xi, yi, aie,
                              s_iou, s_rep);
    }

    // Fold v_i, then 64-lane wave reduction (single wave per block).
    s_iou *= vi;
    s_rep *= vi;
    for (int off = 32; off > 0; off >>= 1) {
        s_iou += __shfl_down(s_iou, off);
        s_rep += __shfl_down(s_rep, off);
    }
    if (tid == 0) {
        part[bid]     = s_iou;
        part[P + bid] = s_rep;
    }
}

__global__ __launch_bounds__(256) void ol_finalize(
    const float* __restrict__ part, int P,
    const float* __restrict__ valid, int n, float* __restrict__ out)
{
    double a = 0.0, b = 0.0, S = 0.0, Q = 0.0;
    for (int k = (int)threadIdx.x; k < P; k += 256) {
        a += (double)part[k];
        b += (double)part[P + k];
    }
    for (int k = (int)threadIdx.x; k < n; k += 256) {
        double v = (double)valid[k];
        S += v;
        Q += v * v;
    }
    __shared__ double sa[256], sb[256], ss[256], sq[256];
    sa[threadIdx.x] = a; sb[threadIdx.x] = b; ss[threadIdx.x] = S; sq[threadIdx.x] = Q;
    __syncthreads();
    for (int s = 128; s > 0; s >>= 1) {
        if ((int)threadIdx.x < s) {
            sa[threadIdx.x] += sa[threadIdx.x + s];
            sb[threadIdx.x] += sb[threadIdx.x + s];
            ss[threadIdx.x] += ss[threadIdx.x + s];
            sq[threadIdx.x] += sq[threadIdx.x + s];
        }
        __syncthreads();
    }
    if (threadIdx.x == 0) {
        double denom = 0.5 * (ss[0] * ss[0] - sq[0]) + 1e-6;   // sum_{i<j} v_i v_j + EPS
        out[0] = (float)(0.5 * ((sa[0] + sb[0]) / denom));     // WEIGHT * RAMP = 0.5
    }
}

extern "C" void kernel_launch(void* const* d_in, const int* in_sizes, int n_in,
                              void* d_out, int out_size, void* d_ws, size_t ws_size,
                              hipStream_t stream) {
    const float* pos   = (const float*)d_in[0];
    const float* size  = (const float*)d_in[1];
    const float* valid = (const float*)d_in[2];
    float* out = (float*)d_out;
    float* ws  = (float*)d_ws;
    int n = in_sizes[2];                 // valid_mask length = N
    int T = (n + TILE - 1) / TILE;       // 128 tiles at N=8192
    int P = T * (T + 1) / 2;             // 8256 upper-triangular tile pairs

    ol_pair_kernel<<<P, TILE, 0, stream>>>(pos, size, valid, ws, n, T, P);
    ol_finalize<<<1, 256, 0, stream>>>(ws, P, valid, n, out);
}

// Round 7
// 36.604 us; speedup vs baseline: 1.2994x; 1.2295x over previous
//
#include <hip/hip_runtime.h>

#define BT 256           // threads per block = 4 waves
#define JT 64            // j-tile width; each wave owns one 64-row i-tile
#define FARV 1.0e7f

template<bool DIAG>
__device__ __forceinline__ void inner_loop(
    const float4* __restrict__ sh_a, const float* __restrict__ sh_ar,
    int lane, float xi, float yi, float hwi, float hhi, float aie,
    float& s_iou, float& s_rep)
{
    const float EPSf = 1e-6f;
    #pragma unroll 16
    for (int t = 0; t < JT; ++t) {
        float4 a  = sh_a[t];      // xj, yj, hwj, hhj (broadcast LDS read)
        float  ar = sh_ar[t];     // areaj

        float dx = xi - a.x;
        float dy = yi - a.y;
        if (DIAG) dx = (t > lane) ? dx : FARV;   // kills both terms for j<=i

        // 1-D overlap: (h1+h2) - max(|dx|, |h1-h2|), clamped at 0.
        float iw = fmaxf((hwi + a.z) - fmaxf(fabsf(dx), fabsf(hwi - a.z)), 0.f);
        float ih = fmaxf((hhi + a.w) - fmaxf(fabsf(dy), fabsf(hhi - a.w)), 0.f);
        float inter = iw * ih;
        float uni   = (aie + ar) - inter;        // >= EPS
        float rc    = __builtin_amdgcn_rcpf(uni);

        float d2   = fmaf(dx, dx, fmaf(dy, dy, EPSf));
        float dist = __builtin_amdgcn_sqrtf(d2);
        float rp   = fmaxf(0.06f - dist, 0.f);

        s_iou = fmaf(inter, rc, s_iou);
        s_rep = fmaf(rp, rp, s_rep);
    }
}

__global__ __launch_bounds__(BT) void ol_pair_kernel(
    const float* __restrict__ pos, const float* __restrict__ size,
    const float* __restrict__ valid, float* __restrict__ part,
    int n, int Tj, int P)
{
    __shared__ float4 sh_a[JT];
    __shared__ float  sh_ar[JT];
    __shared__ float  red_i[4], red_r[4];

    const float EPSf = 1e-6f;
    int tid  = (int)threadIdx.x;
    int lane = tid & 63;
    int wid  = tid >> 6;
    int bid  = (int)blockIdx.x;

    // Decode bid -> (IT, jt): i-group IT covers i-tiles 4IT..4IT+3, j-tiles jt >= 4IT.
    // C(r) = r*(Tj+2) - 2r^2 blocks precede group r.
    float Bf = (float)(Tj + 2);
    float disc = Bf * Bf - 8.f * (float)bid;
    int IT = (int)((Bf - sqrtf(fmaxf(disc, 0.f))) * 0.25f);
    IT = max(0, IT);
    while ((IT + 1) * (Tj + 2) - 2 * (IT + 1) * (IT + 1) <= bid) ++IT;
    while (IT > 0 && IT * (Tj + 2) - 2 * IT * IT > bid) --IT;
    int jt = 4 * IT + (bid - (IT * (Tj + 2) - 2 * IT * IT));

    int my_it = 4 * IT + wid;        // this wave's i-tile
    int i     = my_it * JT + lane;
    int jbase = jt * JT;

    const float2* pos2  = (const float2*)pos;
    const float2* size2 = (const float2*)size;

    // Stage j-tile: invalid/pad boxes pushed to FARV so they contribute 0.
    if (tid < JT) {
        int j = jbase + tid;
        float xj = FARV, yj = FARV, hwj = 0.f, hhj = 0.f, aj = 0.f;
        if (j < n) {
            float2 p = pos2[j];
            float2 s = size2[j];
            float vj = valid[j];
            hwj = 0.5f * s.x;  hhj = 0.5f * s.y;  aj = s.x * s.y;
            if (vj != 0.f) { xj = p.x; yj = p.y; }
        }
        sh_a[tid]  = make_float4(xj, yj, hwj, hhj);
        sh_ar[tid] = aj;
    }

    // This wave's i-box (v_i folded in after the loop).
    float xi = 0.f, yi = 0.f, hwi = 0.f, hhi = 0.f, aie = EPSf, vi = 0.f;
    if (i < n) {
        float2 p = pos2[i];
        float2 s = size2[i];
        xi = p.x;  yi = p.y;
        hwi = 0.5f * s.x;  hhi = 0.5f * s.y;
        aie = s.x * s.y + EPSf;
        vi = valid[i];
    }
    __syncthreads();

    float s_iou = 0.f, s_rep = 0.f;
    if (jt > my_it)
        inner_loop<false>(sh_a, sh_ar, lane, xi, yi, hwi, hhi, aie, s_iou, s_rep);
    else if (jt == my_it)
        inner_loop<true >(sh_a, sh_ar, lane, xi, yi, hwi, hhi, aie, s_iou, s_rep);
    // jt < my_it: this wave's pairs are covered by another block -> contribute 0.

    s_iou *= vi;
    s_rep *= vi;
    for (int off = 32; off > 0; off >>= 1) {
        s_iou += __shfl_down(s_iou, off);
        s_rep += __shfl_down(s_rep, off);
    }
    if (lane == 0) { red_i[wid] = s_iou; red_r[wid] = s_rep; }
    __syncthreads();
    if (tid == 0) {
        part[bid]     = (red_i[0] + red_i[1]) + (red_i[2] + red_i[3]);
        part[P + bid] = (red_r[0] + red_r[1]) + (red_r[2] + red_r[3]);
    }
}

__global__ __launch_bounds__(256) void ol_finalize(
    const float* __restrict__ part, int P,
    const float* __restrict__ valid, int n, float* __restrict__ out)
{
    double a = 0.0, b = 0.0, S = 0.0, Q = 0.0;
    for (int k = (int)threadIdx.x; k < P; k += 256) {
        a += (double)part[k];
        b += (double)part[P + k];
    }
    for (int k = (int)threadIdx.x; k < n; k += 256) {
        double v = (double)valid[k];
        S += v;
        Q += v * v;
    }
    __shared__ double sa[256], sb[256], ss[256], sq[256];
    sa[threadIdx.x] = a; sb[threadIdx.x] = b; ss[threadIdx.x] = S; sq[threadIdx.x] = Q;
    __syncthreads();
    for (int s = 128; s > 0; s >>= 1) {
        if ((int)threadIdx.x < s) {
            sa[threadIdx.x] += sa[threadIdx.x + s];
            sb[threadIdx.x] += sb[threadIdx.x + s];
            ss[threadIdx.x] += ss[threadIdx.x + s];
            sq[threadIdx.x] += sq[threadIdx.x + s];
        }
        __syncthreads();
    }
    if (threadIdx.x == 0) {
        double denom = 0.5 * (ss[0] * ss[0] - sq[0]) + 1e-6;   // sum_{i<j} v_i v_j + EPS
        out[0] = (float)(0.5 * ((sa[0] + sb[0]) / denom));     // WEIGHT * RAMP = 0.5
    }
}

extern "C" void kernel_launch(void* const* d_in, const int* in_sizes, int n_in,
                              void* d_out, int out_size, void* d_ws, size_t ws_size,
                              hipStream_t stream) {
    const float* pos   = (const float*)d_in[0];
    const float* size  = (const float*)d_in[1];
    const float* valid = (const float*)d_in[2];
    float* out = (float*)d_out;
    float* ws  = (float*)d_ws;
    int n  = in_sizes[2];                    // valid_mask length = N
    int Tj = (n + JT - 1) / JT;              // 128 j-tiles
    int Ti = (Tj + 3) / 4;                   // 32 i-groups (4 i-tiles each)
    int P  = Ti * (Tj + 2) - 2 * Ti * Ti;    // 2112 blocks

    ol_pair_kernel<<<P, BT, 0, stream>>>(pos, size, valid, ws, n, Tj, P);
    ol_finalize<<<1, 256, 0, stream>>>(ws, P, valid, n, out);
}

// Round 8
// 35.653 us; speedup vs baseline: 1.3340x; 1.0267x over previous
//
#include <hip/hip_runtime.h>

#define BT 256           // threads per block = 4 waves
#define JT 64            // j-tile width; each wave owns one 64-row i-tile
#define FARV 1.0e7f

template<bool DIAG>
__device__ __forceinline__ void inner_loop(
    const float4* __restrict__ sh_a,
    int lane, float xi, float yi, float hwi, float hhi, float aie,
    float& s_iou, float& s_rep)
{
    const float EPSf = 1e-6f;
    #pragma unroll 8
    for (int t = 0; t < JT; ++t) {
        float4 a = sh_a[t];      // xj, yj, hwj, hhj (broadcast LDS read)

        float dx = xi - a.x;
        float dy = yi - a.y;
        if (DIAG) dx = (t > lane) ? dx : FARV;   // kills both terms for j<=i

        // 1-D overlap: (h1+h2) - max(|dx|, |h1-h2|), clamped at 0.
        float iw = fmaxf((hwi + a.z) - fmaxf(fabsf(dx), fabsf(hwi - a.z)), 0.f);
        float ih = fmaxf((hhi + a.w) - fmaxf(fabsf(dy), fabsf(hhi - a.w)), 0.f);
        float inter = iw * ih;
        // union = area_i + EPS + 4*hwj*hhj - inter   (area_j = 4*hwj*hhj)
        float uni = fmaf(4.f * a.z, a.w, aie - inter);   // >= EPS
        float rc  = __builtin_amdgcn_rcpf(uni);
        s_iou = fmaf(inter, rc, s_iou);

        float d2 = fmaf(dx, dx, fmaf(dy, dy, EPSf));
        if (__any(d2 < 0.0036f)) {               // any lane within repel radius?
            float dist = __builtin_amdgcn_sqrtf(d2);
            float rp   = fmaxf(0.06f - dist, 0.f);
            s_rep = fmaf(rp, rp, s_rep);
        }
    }
}

__global__ __launch_bounds__(BT) void ol_pair_kernel(
    const float* __restrict__ pos, const float* __restrict__ size,
    const float* __restrict__ valid, float* __restrict__ part,
    int n, int Tj, int P)
{
    __shared__ float4 sh_a[JT];
    __shared__ float  red_i[4], red_r[4];

    const float EPSf = 1e-6f;
    int tid  = (int)threadIdx.x;
    int lane = tid & 63;
    int wid  = tid >> 6;
    int bid  = (int)blockIdx.x;

    // Decode bid -> (IT, jt): i-group IT covers i-tiles 4IT..4IT+3, j-tiles jt >= 4IT.
    // C(r) = r*(Tj+2) - 2r^2 blocks precede group r.
    float Bf = (float)(Tj + 2);
    float disc = Bf * Bf - 8.f * (float)bid;
    int IT = (int)((Bf - sqrtf(fmaxf(disc, 0.f))) * 0.25f);
    IT = max(0, IT);
    while ((IT + 1) * (Tj + 2) - 2 * (IT + 1) * (IT + 1) <= bid) ++IT;
    while (IT > 0 && IT * (Tj + 2) - 2 * IT * IT > bid) --IT;
    int jt = 4 * IT + (bid - (IT * (Tj + 2) - 2 * IT * IT));

    int my_it = 4 * IT + wid;        // this wave's i-tile
    int i     = my_it * JT + lane;
    int jbase = jt * JT;

    const float2* pos2  = (const float2*)pos;
    const float2* size2 = (const float2*)size;

    // Stage j-tile: invalid/pad boxes pushed to FARV so both terms vanish.
    if (tid < JT) {
        int j = jbase + tid;
        float xj = FARV, yj = FARV, hwj = 0.f, hhj = 0.f;
        if (j < n) {
            float2 p = pos2[j];
            float2 s = size2[j];
            hwj = 0.5f * s.x;  hhj = 0.5f * s.y;
            if (valid[j] != 0.f) { xj = p.x; yj = p.y; }
        }
        sh_a[tid] = make_float4(xj, yj, hwj, hhj);
    }

    // This wave's i-box (v_i folded in after the loop).
    float xi = 0.f, yi = 0.f, hwi = 0.f, hhi = 0.f, aie = EPSf, vi = 0.f;
    if (i < n) {
        float2 p = pos2[i];
        float2 s = size2[i];
        xi = p.x;  yi = p.y;
        hwi = 0.5f * s.x;  hhi = 0.5f * s.y;
        aie = s.x * s.y + EPSf;
        vi = valid[i];
    }
    __syncthreads();

    float s_iou = 0.f, s_rep = 0.f;
    if (jt > my_it)
        inner_loop<false>(sh_a, lane, xi, yi, hwi, hhi, aie, s_iou, s_rep);
    else if (jt == my_it)
        inner_loop<true >(sh_a, lane, xi, yi, hwi, hhi, aie, s_iou, s_rep);
    // jt < my_it: this wave's pairs are covered by another block -> contribute 0.

    s_iou *= vi;
    s_rep *= vi;
    for (int off = 32; off > 0; off >>= 1) {
        s_iou += __shfl_down(s_iou, off);
        s_rep += __shfl_down(s_rep, off);
    }
    if (lane == 0) { red_i[wid] = s_iou; red_r[wid] = s_rep; }
    __syncthreads();
    if (tid == 0) {
        part[bid]     = (red_i[0] + red_i[1]) + (red_i[2] + red_i[3]);
        part[P + bid] = (red_r[0] + red_r[1]) + (red_r[2] + red_r[3]);
    }
}

__global__ __launch_bounds__(256) void ol_finalize(
    const float* __restrict__ part, int P,
    const float* __restrict__ valid, int n, float* __restrict__ out)
{
    int tid = (int)threadIdx.x;
    double a = 0.0, b = 0.0, S = 0.0, Q = 0.0;
    for (int k = tid; k < P; k += 256) {
        a += (double)part[k];
        b += (double)part[P + k];
    }
    for (int k = tid; k < n; k += 256) {
        double v = (double)valid[k];
        S += v;
        Q += v * v;
    }
    for (int off = 32; off > 0; off >>= 1) {
        a += __shfl_down(a, off);
        b += __shfl_down(b, off);
        S += __shfl_down(S, off);
        Q += __shfl_down(Q, off);
    }
    __shared__ double red[4][4];
    int lane = tid & 63, wid = tid >> 6;
    if (lane == 0) { red[0][wid] = a; red[1][wid] = b; red[2][wid] = S; red[3][wid] = Q; }
    __syncthreads();
    if (tid == 0) {
        a = red[0][0] + red[0][1] + red[0][2] + red[0][3];
        b = red[1][0] + red[1][1] + red[1][2] + red[1][3];
        S = red[2][0] + red[2][1] + red[2][2] + red[2][3];
        Q = red[3][0] + red[3][1] + red[3][2] + red[3][3];
        double denom = 0.5 * (S * S - Q) + 1e-6;            // sum_{i<j} v_i v_j + EPS
        out[0] = (float)(0.5 * ((a + b) / denom));          // WEIGHT * RAMP = 0.5
    }
}

extern "C" void kernel_launch(void* const* d_in, const int* in_sizes, int n_in,
                              void* d_out, int out_size, void* d_ws, size_t ws_size,
                              hipStream_t stream) {
    const float* pos   = (const float*)d_in[0];
    const float* size  = (const float*)d_in[1];
    const float* valid = (const float*)d_in[2];
    float* out = (float*)d_out;
    float* ws  = (float*)d_ws;
    int n  = in_sizes[2];                    // valid_mask length = N
    int Tj = (n + JT - 1) / JT;              // 128 j-tiles
    int Ti = (Tj + 3) / 4;                   // 32 i-groups (4 i-tiles each)
    int P  = Ti * (Tj + 2) - 2 * Ti * Ti;    // 2112 blocks

    ol_pair_kernel<<<P, BT, 0, stream>>>(pos, size, valid, ws, n, Tj, P);
    ol_finalize<<<1, 256, 0, stream>>>(ws, P, valid, n, out);
}